// Round 10
// baseline (113.433 us; speedup 1.0000x reference)
//
#include <hip/hip_runtime.h>
#include <math.h>

#define DD 128
#define BB 8192
#define NN 64
#define BT 64                      // kernel-B b-tile per block (R10: was 128)
#define LOGC 235.24826450039622f   // 128 * log(2*pi)
#define CLAMP_M 1.0e12f            // clamp on solve outputs: keeps all downstream f32 finite (no NaN)
#define YCLAMP 1.0e18f             // fallback-path clamp
#define KP 136                     // kernel-B LDS pitch in bf16 elements (128 + 8 pad)
#define PITCH 129                  // kernel-A LDS pitch in f32 (stride mod 32 = 1)

typedef __attribute__((ext_vector_type(8))) short bf16x8;   // 8 bf16 = 4 VGPRs
typedef __attribute__((ext_vector_type(4))) float f32x4;

__device__ __forceinline__ unsigned int f2bf(float x) {
    unsigned int u = __float_as_uint(x);
    return (u + 0x7FFFu + ((u >> 16) & 1u)) >> 16;
}
__device__ __forceinline__ unsigned int pack2(float lo, float hi) {
    return f2bf(lo) | (f2bf(hi) << 16);
}
__device__ __forceinline__ float clampM(float x) {
    return fminf(fmaxf(x, -CLAMP_M), CLAMP_M);
}
__device__ __forceinline__ float lane_bcast(float v, int j) {
    return __int_as_float(__builtin_amdgcn_readlane(__float_as_int(v), j));
}

// ---------------------------------------------------------------------------
// Kernel A (byte-identical to R7/R9, ~5-11 us by ledger): 8 column-chains per
// wave. Grid (5, 64). Kept unchanged for clean attribution of B's delta.
// ---------------------------------------------------------------------------
__global__ __launch_bounds__(256, 2)
void solve_columns(const float* __restrict__ chol,
                   const float* __restrict__ means,
                   unsigned short* __restrict__ Mout,  // (N,D,D) bf16 row-major
                   float* __restrict__ vout,           // (N,D)
                   float* __restrict__ termout)        // (N)
{
    const int n = blockIdx.y;
    const int grp = blockIdx.x;      // 0..4
    const int t = threadIdx.x;
    const int lane = t & 63;
    const int w = t >> 6;
    const float* __restrict__ Ln = chol + (size_t)n * DD * DD;

    const bool is_mu = (grp == 4);
    const int jmin = is_mu ? 0 : grp * 32;   // LsT rows below this never read

    __shared__ float LsT[DD][PITCH];   // [j][i] = (i>j) ? L[i][j] : 0
    __shared__ float s_invd[DD];
    __shared__ float s_raw[DD];

    #pragma unroll
    for (int it = 0; it < 16; ++it) {
        const int id = it * 256 + t;        // 4096 float4 chunks
        const int i = id >> 5;              // row of L
        const int j0 = (id & 31) * 4;       // col of L
        if (j0 < jmin) continue;
        if (i <= j0) {
            LsT[j0 + 0][i] = 0.0f;
            LsT[j0 + 1][i] = 0.0f;
            LsT[j0 + 2][i] = 0.0f;
            LsT[j0 + 3][i] = 0.0f;
        } else {
            const float4 vv = *(const float4*)(Ln + (size_t)i * DD + j0);
            LsT[j0 + 0][i] = (i > j0 + 0) ? vv.x : 0.0f;
            LsT[j0 + 1][i] = (i > j0 + 1) ? vv.y : 0.0f;
            LsT[j0 + 2][i] = (i > j0 + 2) ? vv.z : 0.0f;
            LsT[j0 + 3][i] = (i > j0 + 3) ? vv.w : 0.0f;
        }
    }
    if (t < DD) {
        const float raw = Ln[(size_t)t * DD + t];
        s_raw[t] = raw;
        s_invd[t] = __expf(-raw);           // 1/exp(raw): diag of L is exp(raw)
    }
    __syncthreads();

    if (is_mu) {
        if (w == 0) {
            float rl = means[(size_t)n * DD + lane];
            float rh = means[(size_t)n * DD + 64 + lane];
            #pragma unroll 4
            for (int j = 0; j < 64; ++j) {
                const float y = clampM(lane_bcast(rl, j) * s_invd[j]);
                rl = fmaf(-LsT[j][lane], y, rl);
                rh = fmaf(-LsT[j][64 + lane], y, rh);
            }
            #pragma unroll 4
            for (int j = 64; j < 128; ++j) {
                const float y = clampM(lane_bcast(rh, j - 64) * s_invd[j]);
                rh = fmaf(-LsT[j][64 + lane], y, rh);
            }
            vout[(size_t)n * DD + lane] = clampM(rl * s_invd[lane]);
            vout[(size_t)n * DD + 64 + lane] = clampM(rh * s_invd[64 + lane]);
        } else if (w == 1) {
            float v = s_raw[lane] + s_raw[64 + lane];
            #pragma unroll
            for (int o = 32; o > 0; o >>= 1) v += __shfl_down(v, o);
            if (lane == 0) termout[n] = LOGC + 2.0f * v;
        }
        return;
    }

    const int c0 = grp * 32 + w * 8;
    float rl[8], rh[8];
    #pragma unroll
    for (int ch = 0; ch < 8; ++ch) {
        rl[ch] = (lane == c0 + ch) ? 1.0f : 0.0f;
        rh[ch] = (lane + 64 == c0 + ch) ? 1.0f : 0.0f;
    }

    #pragma unroll 2
    for (int j = c0; j < 64; ++j) {
        const float invd = s_invd[j];
        const float Ll = LsT[j][lane];
        const float Lh = LsT[j][64 + lane];
        float yv[8];
        #pragma unroll
        for (int ch = 0; ch < 8; ++ch)
            yv[ch] = clampM(lane_bcast(rl[ch], j) * invd);
        #pragma unroll
        for (int ch = 0; ch < 8; ++ch) {
            rl[ch] = fmaf(-Ll, yv[ch], rl[ch]);
            rh[ch] = fmaf(-Lh, yv[ch], rh[ch]);
        }
    }
    #pragma unroll 2
    for (int j = (c0 > 64 ? c0 : 64); j < 128; ++j) {
        const float invd = s_invd[j];
        const float Lh = LsT[j][64 + lane];
        float yv[8];
        #pragma unroll
        for (int ch = 0; ch < 8; ++ch)
            yv[ch] = clampM(lane_bcast(rh[ch], j - 64) * invd);
        #pragma unroll
        for (int ch = 0; ch < 8; ++ch)
            rh[ch] = fmaf(-Lh, yv[ch], rh[ch]);
    }

    const float i_lo = s_invd[lane], i_hi = s_invd[64 + lane];
    float ylo[8], yhi[8];
    #pragma unroll
    for (int ch = 0; ch < 8; ++ch) {
        ylo[ch] = clampM(rl[ch] * i_lo);
        yhi[ch] = clampM(rh[ch] * i_hi);
    }
    uint4 plo, phi;
    plo.x = pack2(ylo[0], ylo[1]); plo.y = pack2(ylo[2], ylo[3]);
    plo.z = pack2(ylo[4], ylo[5]); plo.w = pack2(ylo[6], ylo[7]);
    phi.x = pack2(yhi[0], yhi[1]); phi.y = pack2(yhi[2], yhi[3]);
    phi.z = pack2(yhi[4], yhi[5]); phi.w = pack2(yhi[6], yhi[7]);
    *(uint4*)&Mout[((size_t)n * DD + lane) * DD + c0] = plo;
    *(uint4*)&Mout[((size_t)n * DD + 64 + lane) * DD + c0] = phi;
}

// ---------------------------------------------------------------------------
// Kernel B (R10 restructure for TLP): quad[b,n] = ||M_n x_b - v_n||^2.
// R9 post-mortem: spill-B, DMA-B, sync-B all ~40-50 us; common denominator is
// 2 blocks/CU (75 KB LDS) -> 2 waves/SIMD -> ~88% stall (R5 counters: MfmaUtil
// 11.6, VALUBusy 12.2, Occ 16%). Fix: b-tile 64 (acc 32 VGPR, ~145 total),
// single M-buffer reused for x-staging (LDS 43 KB), launch_bounds(256,3),
// grid (128,8)=1024 blocks -> 3 blocks/CU, 50% more latency cover.
// ---------------------------------------------------------------------------
__global__ __launch_bounds__(256, 3)
void emission_mfma(const float* __restrict__ x,
                   const unsigned short* __restrict__ Mws,
                   const float* __restrict__ vws,
                   const float* __restrict__ termws,
                   float* __restrict__ out)
{
    const int btile = blockIdx.x;            // 128 tiles of 64 b
    const int ngrp = blockIdx.y;             // 8 groups of 8 n
    const int t = threadIdx.x;
    const int lane = t & 63;
    const int w = t >> 6;                    // wave w owns i-rows w*32..w*32+31

    __shared__ __align__(16) unsigned short Ms[128 * KP]; // M tile; x overlay in prologue
    __shared__ __align__(16) float sv8[8 * DD];           // v for the 8 n
    __shared__ float qbuf[8 * BT];
    __shared__ float redbuf[2][4 * BT];                   // [parity][wave][64 b]
    __shared__ float sterm[8];

    const int bbase = btile * BT;

    // --- prologue: stage x (BT x 128) as bf16 into Ms overlay; sv8; sterm ---
    #pragma unroll
    for (int it = 0; it < 4; ++it) {
        const int id = it * 256 + t;         // 1024 chunks of 8 elems
        const int brow = id >> 4;            // 0..63
        const int koff = (id & 15) * 8;
        const float4* px = (const float4*)(x + (size_t)(bbase + brow) * DD + koff);
        const float4 a = px[0], b = px[1];
        uint4 p;
        p.x = pack2(a.x, a.y);
        p.y = pack2(a.z, a.w);
        p.z = pack2(b.x, b.y);
        p.w = pack2(b.z, b.w);
        *(uint4*)&Ms[brow * KP + koff] = p;
    }
    *(float4*)&sv8[4 * t] = *(const float4*)&vws[(size_t)ngrp * 8 * DD + 4 * t];
    if (t < 8) sterm[t] = termws[ngrp * 8 + t];
    __syncthreads();

    // --- preload x frags (B-operand): 4 b-tiles x 4 k-steps ---
    bf16x8 bf[4][4];
    #pragma unroll
    for (int bt = 0; bt < 4; ++bt)
        #pragma unroll
        for (int ks = 0; ks < 4; ++ks) {
            const int col = bt * 16 + (lane & 15);          // b within tile
            const int k = ks * 32 + (lane >> 4) * 8;
            bf[bt][ks] = *(const bf16x8*)&Ms[col * KP + k];
        }
    __syncthreads();   // frags read; Ms free for M staging

    const f32x4 zero = {0.0f, 0.0f, 0.0f, 0.0f};

    for (int nl = 0; nl < 8; ++nl) {
        // --- stage M_n (sync, coalesced) + fold previous reduction ---
        const unsigned short* __restrict__ Mn =
            Mws + (size_t)(ngrp * 8 + nl) * DD * DD;
        #pragma unroll
        for (int it = 0; it < 8; ++it) {
            const int id = it * 256 + t;     // 2048 chunks of 8
            const int row = id >> 4;
            const int koff = (id & 15) * 8;
            *(uint4*)&Ms[row * KP + koff] = *(const uint4*)&Mn[row * DD + koff];
        }
        if (nl > 0 && t < BT) {
            const float* rb = redbuf[(nl - 1) & 1];
            qbuf[(nl - 1) * BT + t] = rb[t] + rb[BT + t] + rb[2 * BT + t] + rb[3 * BT + t];
        }
        __syncthreads();

        // --- MFMA: C[128i x 64b], wave w covers rows w*32..+31, K=128 ---
        f32x4 acc[2][4];
        #pragma unroll
        for (int it = 0; it < 2; ++it)
            #pragma unroll
            for (int bt = 0; bt < 4; ++bt) acc[it][bt] = zero;

        #pragma unroll
        for (int ks = 0; ks < 4; ++ks) {
            bf16x8 af[2];
            #pragma unroll
            for (int it = 0; it < 2; ++it) {
                const int row = w * 32 + it * 16 + (lane & 15);
                const int k = ks * 32 + (lane >> 4) * 8;
                af[it] = *(const bf16x8*)&Ms[row * KP + k];
            }
            #pragma unroll
            for (int it = 0; it < 2; ++it)
                #pragma unroll
                for (int bt = 0; bt < 4; ++bt)
                    acc[it][bt] = __builtin_amdgcn_mfma_f32_16x16x32_bf16(
                        af[it], bf[bt][ks], acc[it][bt], 0, 0, 0);
        }

        // --- epilogue: p[b] += (y - v)^2 over this wave's 32 rows ---
        float p[4] = {0.0f, 0.0f, 0.0f, 0.0f};
        #pragma unroll
        for (int it = 0; it < 2; ++it) {
            const int rowbase = w * 32 + it * 16 + (lane >> 4) * 4;  // C row = q*4+reg
            const f32x4 v4 = *(const f32x4*)&sv8[nl * DD + rowbase];
            #pragma unroll
            for (int bt = 0; bt < 4; ++bt) {
                const f32x4 a = acc[it][bt];
                const float t0 = a.x - v4.x, t1 = a.y - v4.y;
                const float t2 = a.z - v4.z, t3 = a.w - v4.w;
                p[bt] += t0 * t0 + t1 * t1 + t2 * t2 + t3 * t3;
            }
        }
        float* rb = redbuf[nl & 1];
        #pragma unroll
        for (int bt = 0; bt < 4; ++bt) {
            float pv = p[bt];
            pv += __shfl_xor(pv, 16);   // fold row-quad groups (same b-col)
            pv += __shfl_xor(pv, 32);
            if (lane < 16) rb[w * BT + bt * 16 + lane] = pv;
        }
        __syncthreads();   // Ms consumed; redbuf[nl&1] complete
    }

    // --- final: fold nl=7 (parity 1), write out[b][n0..n0+7] ---
    if (t < BT) {
        const float* rb = redbuf[1];
        qbuf[7 * BT + t] = rb[t] + rb[BT + t] + rb[2 * BT + t] + rb[3 * BT + t];
        float o[8];
        #pragma unroll
        for (int j = 0; j < 8; ++j)
            o[j] = -0.5f * (sterm[j] + qbuf[j * BT + t]);
        float* po = &out[(size_t)(bbase + t) * NN + ngrp * 8];
        *(float4*)&po[0] = make_float4(o[0], o[1], o[2], o[3]);
        *(float4*)&po[4] = make_float4(o[4], o[5], o[6], o[7]);
    }
}

// ---------------------------------------------------------------------------
// Fallback if workspace is too small: direct per-(b,n) solve (R2 path).
// ---------------------------------------------------------------------------
__global__ __launch_bounds__(256, 2)
void emission_solve_fb(const float* __restrict__ xin,
                       const float* __restrict__ means,
                       const float* __restrict__ chol,
                       float* __restrict__ out)
{
    const int n = blockIdx.y;
    const int t = threadIdx.x;
    const int b = blockIdx.x * 256 + t;
    const float* __restrict__ Ln = chol + (size_t)n * DD * DD;

    __shared__ float s_invd[DD];
    __shared__ float s_mu[DD];
    __shared__ float s_part[4];

    float raw = 0.0f;
    if (t < DD) {
        raw = Ln[t * DD + t];
        s_invd[t] = 1.0f / expf(raw);
        s_mu[t] = means[n * DD + t];
    }
    float v = raw;
    #pragma unroll
    for (int o = 32; o > 0; o >>= 1) v += __shfl_down(v, o);
    if ((t & 63) == 0) s_part[t >> 6] = v;
    __syncthreads();

    const float term = LOGC + 2.0f * (s_part[0] + s_part[1] + s_part[2] + s_part[3]);

    float y[DD];
    float quad = 0.0f;
    #pragma unroll
    for (int i = 0; i < DD; ++i) {
        const float xv = xin[(size_t)b * DD + i] - s_mu[i];
        float sA = 0.0f, sB = 0.0f;
        #pragma unroll
        for (int j = 0; j + 1 < i; j += 2) {
            sA = fmaf(Ln[i * DD + j], y[j], sA);
            sB = fmaf(Ln[i * DD + j + 1], y[j + 1], sB);
        }
        if (i & 1) sA = fmaf(Ln[i * DD + (i - 1)], y[i - 1], sA);
        const float s = xv - sA - sB;
        float yi = s * s_invd[i];
        yi = fminf(fmaxf(yi, -YCLAMP), YCLAMP);
        y[i] = yi;
        quad = fmaf(yi, yi, quad);
    }
    out[(size_t)b * NN + n] = -0.5f * (term + quad);
}

extern "C" void kernel_launch(void* const* d_in, const int* in_sizes, int n_in,
                              void* d_out, int out_size, void* d_ws, size_t ws_size,
                              hipStream_t stream) {
    const float* x     = (const float*)d_in[0];  // (8192,128)
    const float* means = (const float*)d_in[1];  // (64,128)
    const float* chol  = (const float*)d_in[2];  // (64,128,128)
    float* out = (float*)d_out;                  // (8192,64)

    const size_t needM = (size_t)NN * DD * DD * sizeof(unsigned short); // 2 MiB
    const size_t needV = (size_t)NN * DD * sizeof(float);               // 32 KiB
    const size_t needT = (size_t)NN * sizeof(float);

    if (ws_size >= needM + needV + needT) {
        unsigned short* Mws = (unsigned short*)d_ws;
        float* vws = (float*)((char*)d_ws + needM);
        float* tws = (float*)((char*)d_ws + needM + needV);
        solve_columns<<<dim3(5, NN), 256, 0, stream>>>(chol, means, Mws, vws, tws);
        emission_mfma<<<dim3(BB / BT, 8), 256, 0, stream>>>(x, Mws, vws, tws, out);
    } else {
        emission_solve_fb<<<dim3(BB / 256, NN), 256, 0, stream>>>(x, means, chol, out);
    }
}